// Round 4
// baseline (353.287 us; speedup 1.0000x reference)
//
#include <hip/hip_runtime.h>
#include <math.h>

#define S 2048
#define B 16
#define H 512
#define L 4096
#define SMAX 16
#define LAB 256
#define V 32000
#define NCH 250          // V / 128 vocab chunks
#define LOG2E 1.44269504f

typedef __attribute__((ext_vector_type(8))) short short8;
typedef __attribute__((ext_vector_type(4))) float float4v;

__device__ inline ushort f2bf(float x) {
  union { float f; unsigned u; } c; c.f = x;
  unsigned r = c.u + 0x7fffu + ((c.u >> 16) & 1u);
  return (ushort)(r >> 16);
}
__device__ inline float bf2f(ushort h) {
  union { unsigned u; float f; } c; c.u = ((unsigned)h) << 16;
  return c.f;
}

// ---------------------------------------------------------------- kernel A
// span gather -> spanb bf16 [L][1536] = concat(left, mean, right)
__global__ __launch_bounds__(256) void spanb_kernel(
    const float* __restrict__ hidden, const int* __restrict__ begins,
    const int* __restrict__ ends, const int* __restrict__ bids,
    ushort* __restrict__ spanb) {
  int sub = threadIdx.x >> 7, t = threadIdx.x & 127;
  int l = blockIdx.x * 2 + sub;
  int b = bids[l], s0 = begins[l], s1 = ends[l];
  const float4* hidv = (const float4*)hidden;
  float4 lf = hidv[((size_t)(s0 - 1) * B + b) * 128 + t];
  float4 rf = hidv[((size_t)s1 * B + b) * 128 + t];
  float4 m = make_float4(0.f, 0.f, 0.f, 0.f);
  int len = s1 - s0;
  for (int j = 0; j < len; ++j) {
    float4 g = hidv[((size_t)(s0 + j) * B + b) * 128 + t];
    m.x += g.x; m.y += g.y; m.z += g.z; m.w += g.w;
  }
  float inv = 1.0f / (float)len;
  ushort* sp = spanb + (size_t)l * 1536;
  ushort4 u;
  u.x = f2bf(lf.x); u.y = f2bf(lf.y); u.z = f2bf(lf.z); u.w = f2bf(lf.w);
  *(ushort4*)&sp[t * 4] = u;
  u.x = f2bf(m.x * inv); u.y = f2bf(m.y * inv);
  u.z = f2bf(m.z * inv); u.w = f2bf(m.w * inv);
  *(ushort4*)&sp[512 + t * 4] = u;
  u.x = f2bf(rf.x); u.y = f2bf(rf.y); u.z = f2bf(rf.z); u.w = f2bf(rf.w);
  *(ushort4*)&sp[1024 + t * 4] = u;
}

// ---------------------------------------------------------------- kernel B
// generic transpose+cast: src[K][N] f32 -> dst[N][K] bf16 (W1, W2)
__global__ __launch_bounds__(256) void tcast_kernel(
    const float* __restrict__ src, ushort* __restrict__ dst, int K, int N) {
  __shared__ ushort tile[64 * 72];
  int t = threadIdx.x;
  int n0 = blockIdx.x * 64;
  int k0 = blockIdx.y * 64;
  #pragma unroll
  for (int p = 0; p < 16; ++p) {
    int k = p * 4 + (t >> 6);
    int n = t & 63;
    tile[n * 72 + k] = f2bf(src[(size_t)(k0 + k) * N + n0 + n]);
  }
  __syncthreads();
  #pragma unroll
  for (int p = 0; p < 2; ++p) {
    int idx = p * 256 + t;
    int n = idx >> 3, c = idx & 7;
    *(uint4*)&dst[(size_t)(n0 + n) * K + k0 + c * 8] =
        *(const uint4*)&tile[n * 72 + c * 8];
  }
}

// ---------------------------------------------------------------- kernel B2
// Wo [256][32000] f32 -> fragment-major bf16 Wob:
//   frag f = (((c*2+kh)*4 + k4)*8 + nt)*64 + lq*16 + lr, 8 ushorts each,
//   where v = c*128 + nt*16 + lr, k = kh*128 + k4*32 + lq*8 + e.
__global__ __launch_bounds__(256) void tcast_wo_kernel(
    const float* __restrict__ src, ushort* __restrict__ dst) {
  __shared__ ushort tile[64 * 72];
  int t = threadIdx.x;
  int n0 = blockIdx.x * 64;            // vocab
  int k0 = blockIdx.y * 64;            // K
  #pragma unroll
  for (int p = 0; p < 16; ++p) {
    int k = p * 4 + (t >> 6);
    int n = t & 63;
    tile[n * 72 + k] = f2bf(src[(size_t)(k0 + k) * V + n0 + n]);
  }
  __syncthreads();
  #pragma unroll
  for (int p = 0; p < 2; ++p) {
    int idx = p * 256 + t;             // 512 uint4 per tile
    int n = idx >> 3, c8 = idx & 7;
    int v = n0 + n, k = k0 + c8 * 8;
    int c = v >> 7, nt = (v >> 4) & 7, lr = v & 15;
    int kh = k >> 7, k4 = (k >> 5) & 3, lq = (k >> 3) & 3;
    size_t f = ((((size_t)c * 2 + kh) * 4 + k4) * 8 + nt) * 64 + lq * 16 + lr;
    *(uint4*)&dst[f * 8] = *(const uint4*)&tile[n * 72 + c8 * 8];
  }
}

// ---------------------------------------------------------------- kernel C
// MFMA MLP: featb = bf16( sigmoid(spanb@W1+b1) @ W2 + b2 )
#define FST 72
__global__ __launch_bounds__(256, 2) void feat_mfma_kernel(
    const ushort* __restrict__ spanb, const ushort* __restrict__ W1b,
    const float* __restrict__ b1, const ushort* __restrict__ W2b,
    const float* __restrict__ b2, ushort* __restrict__ featb) {
  __shared__ ushort As[32 * FST];
  __shared__ ushort Bs[256 * FST];
  __shared__ ushort Hs[32 * 264];
  int tid = threadIdx.x;
  int w = tid >> 6, lane = tid & 63;
  int lr = lane & 15, lq = lane >> 4;
  int l0 = blockIdx.x * 32;

  float4v acc[2][4];
  float4v zero = {0.f, 0.f, 0.f, 0.f};
  #pragma unroll
  for (int mt = 0; mt < 2; ++mt)
    #pragma unroll
    for (int nt = 0; nt < 4; ++nt) acc[mt][nt] = zero;

  for (int s = 0; s < 24; ++s) {
    int ks = s * 64;
    __syncthreads();
    {
      int r = tid >> 3, c = tid & 7;
      *(uint4*)&As[r * FST + c * 8] =
          *(const uint4*)&spanb[(size_t)(l0 + r) * 1536 + ks + c * 8];
    }
    #pragma unroll
    for (int p = 0; p < 8; ++p) {
      int idx = p * 256 + tid;
      int r = idx >> 3, c = idx & 7;
      *(uint4*)&Bs[r * FST + c * 8] =
          *(const uint4*)&W1b[(size_t)r * 1536 + ks + c * 8];
    }
    __syncthreads();
    #pragma unroll
    for (int kk = 0; kk < 2; ++kk) {
      short8 af[2], bf[4];
      #pragma unroll
      for (int mt = 0; mt < 2; ++mt)
        af[mt] = *(const short8*)&As[(mt * 16 + lr) * FST + kk * 32 + lq * 8];
      #pragma unroll
      for (int nt = 0; nt < 4; ++nt)
        bf[nt] = *(const short8*)
            &Bs[(w * 64 + nt * 16 + lr) * FST + kk * 32 + lq * 8];
      #pragma unroll
      for (int mt = 0; mt < 2; ++mt)
        #pragma unroll
        for (int nt = 0; nt < 4; ++nt)
          acc[mt][nt] = __builtin_amdgcn_mfma_f32_16x16x32_bf16(
              af[mt], bf[nt], acc[mt][nt], 0, 0, 0);
    }
  }

  {
    float b1v[4];
    #pragma unroll
    for (int nt = 0; nt < 4; ++nt) b1v[nt] = b1[w * 64 + nt * 16 + lr];
    #pragma unroll
    for (int mt = 0; mt < 2; ++mt)
      #pragma unroll
      for (int nt = 0; nt < 4; ++nt)
        #pragma unroll
        for (int r = 0; r < 4; ++r) {
          int row = mt * 16 + lq * 4 + r;
          int col = w * 64 + nt * 16 + lr;
          float h = 1.0f / (1.0f + __expf(-(acc[mt][nt][r] + b1v[nt])));
          Hs[row * 264 + col] = f2bf(h);
        }
  }

  float4v acc2[2][4];
  #pragma unroll
  for (int mt = 0; mt < 2; ++mt)
    #pragma unroll
    for (int nt = 0; nt < 4; ++nt) acc2[mt][nt] = zero;

  for (int s = 0; s < 4; ++s) {
    int ks = s * 64;
    __syncthreads();
    #pragma unroll
    for (int p = 0; p < 8; ++p) {
      int idx = p * 256 + tid;
      int r = idx >> 3, c = idx & 7;
      *(uint4*)&Bs[r * FST + c * 8] =
          *(const uint4*)&W2b[(size_t)r * 256 + ks + c * 8];
    }
    __syncthreads();
    #pragma unroll
    for (int kk = 0; kk < 2; ++kk) {
      short8 af[2], bf[4];
      #pragma unroll
      for (int mt = 0; mt < 2; ++mt)
        af[mt] = *(const short8*)
            &Hs[(mt * 16 + lr) * 264 + ks + kk * 32 + lq * 8];
      #pragma unroll
      for (int nt = 0; nt < 4; ++nt)
        bf[nt] = *(const short8*)
            &Bs[(w * 64 + nt * 16 + lr) * FST + kk * 32 + lq * 8];
      #pragma unroll
      for (int mt = 0; mt < 2; ++mt)
        #pragma unroll
        for (int nt = 0; nt < 4; ++nt)
          acc2[mt][nt] = __builtin_amdgcn_mfma_f32_16x16x32_bf16(
              af[mt], bf[nt], acc2[mt][nt], 0, 0, 0);
    }
  }

  {
    float b2v[4];
    #pragma unroll
    for (int nt = 0; nt < 4; ++nt) b2v[nt] = b2[w * 64 + nt * 16 + lr];
    #pragma unroll
    for (int mt = 0; mt < 2; ++mt)
      #pragma unroll
      for (int nt = 0; nt < 4; ++nt)
        #pragma unroll
        for (int r = 0; r < 4; ++r) {
          int row = mt * 16 + lq * 4 + r;
          int col = w * 64 + nt * 16 + lr;
          featb[(size_t)(l0 + row) * 256 + col] =
              f2bf(acc2[mt][nt][r] + b2v[nt]);
        }
  }
}

// ---------------------------------------------------------------- kernel D
// logits + sumexp partials. Round-3 structure retained (frag-major Wob,
// linear global_load_lds staging, conflict-free ds_read, x-fastest grid),
// wave tile rebalanced 32x128 -> 128 labels x 64 vocab (mt=8, nt=4):
//  - LDS B-bytes per MFMA halved (block LDS-read 256KB -> 128KB per 64KB
//    chunk): round-3's largest pipe cost was ~40us/CU of ds_read_b128
//  - full 128-vocab chunk staged once, ONE barrier (round-3 had 3)
//  - ds_read addr = single base + 16-bit immediate (kg*8192 + nt*1024)
//  - both vocab-half waves produce partials for the same label rows ->
//    pz gains a wv axis: [ch][2][L]; reduce sums 500 partials
__global__ __launch_bounds__(256, 2) void logits2_kernel(
    const ushort* __restrict__ featb, const ushort* __restrict__ Wob,
    const float* __restrict__ bo, float* __restrict__ pz) {
  __shared__ ushort Blds[32768];         // 64 KB: full chunk, frag-major
  int tid = threadIdx.x;
  int lane = tid & 63;
  int wl = tid >> 7;                     // label half  (0..1) -> 128 rows
  int wv = (tid >> 6) & 1;               // vocab half  (0..1) -> 64 cols
  int lr = lane & 15, lq = lane >> 4;
  int l0 = blockIdx.x * 256;
  int v0 = blockIdx.y * 128;

  // A base: row (l0 + wl*128 + mt*16 + lr), col lq*8. short8 units:
  // mt stride = 16 rows = 512, kg stride = 32 ushorts = 4.
  const short8* abase = (const short8*)(featb +
      (size_t)(l0 + wl * 128 + lr) * 256 + lq * 8);

  short8 af[2][8];
  #pragma unroll
  for (int mt = 0; mt < 8; ++mt) af[0][mt] = abase[mt * 512];

  // stage full chunk: 4096 frags x 16B, pure linear copy, async to LDS
  {
    const uint4* src4 = (const uint4*)(Wob + (size_t)blockIdx.y * 32768);
    #pragma unroll
    for (int p = 0; p < 16; ++p) {
      int idx = p * 256 + tid;
      __builtin_amdgcn_global_load_lds(
          (const __attribute__((address_space(1))) unsigned int*)(src4 + idx),
          (__attribute__((address_space(3))) unsigned int*)&Blds[idx * 8],
          16, 0, 0);
    }
  }

  float4v acc[8][4];
  float4v zero = {0.f, 0.f, 0.f, 0.f};
  #pragma unroll
  for (int mt = 0; mt < 8; ++mt)
    #pragma unroll
    for (int nt = 0; nt < 4; ++nt) acc[mt][nt] = zero;

  __syncthreads();                       // the only barrier (drains DMA)

  // B frag (kg, wv*4+nt): ushort off = (kg*8 + wv*4 + nt)*64*8 + lane*8
  const ushort* bbase = &Blds[(wv * 4 * 64 + lane) * 8];

  #pragma unroll
  for (int kg = 0; kg < 8; ++kg) {       // K = 8 steps of 32
    int cur = kg & 1, nxt = cur ^ 1;
    if (kg < 7) {
      #pragma unroll
      for (int mt = 0; mt < 8; ++mt)
        af[nxt][mt] = abase[mt * 512 + (kg + 1) * 4];
    }
    short8 bf[4];
    #pragma unroll
    for (int nt = 0; nt < 4; ++nt)
      bf[nt] = *(const short8*)&bbase[kg * 4096 + nt * 512];
    __builtin_amdgcn_s_setprio(1);
    #pragma unroll
    for (int mt = 0; mt < 8; ++mt)
      #pragma unroll
      for (int nt = 0; nt < 4; ++nt)
        acc[mt][nt] = __builtin_amdgcn_mfma_f32_16x16x32_bf16(
            af[cur][mt], bf[nt], acc[mt][nt], 0, 0, 0);
    __builtin_amdgcn_s_setprio(0);
  }

  // epilogue: z[row] = sum_cols exp(logit + bo), no max (logits bounded)
  float bov[4];
  #pragma unroll
  for (int nt = 0; nt < 4; ++nt)
    bov[nt] = bo[v0 + wv * 64 + nt * 16 + lr] * LOG2E;
  float z[8][4];
  #pragma unroll
  for (int mt = 0; mt < 8; ++mt)
    #pragma unroll
    for (int r = 0; r < 4; ++r) z[mt][r] = 0.f;
  #pragma unroll
  for (int mt = 0; mt < 8; ++mt)
    #pragma unroll
    for (int nt = 0; nt < 4; ++nt)
      #pragma unroll
      for (int r = 0; r < 4; ++r)
        z[mt][r] += exp2f(fmaf(acc[mt][nt][r], LOG2E, bov[nt]));
  #pragma unroll
  for (int mt = 0; mt < 8; ++mt)
    #pragma unroll
    for (int r = 0; r < 4; ++r) {
      #pragma unroll
      for (int off = 1; off < 16; off <<= 1)
        z[mt][r] += __shfl_xor(z[mt][r], off);
    }
  if (lr == 0) {
    int slot = blockIdx.y * 2 + wv;
    #pragma unroll
    for (int mt = 0; mt < 8; ++mt) {
      float4 v4;
      v4.x = z[mt][0]; v4.y = z[mt][1]; v4.z = z[mt][2]; v4.w = z[mt][3];
      *(float4*)&pz[(size_t)slot * L + l0 + wl * 128 + mt * 16 + lq * 4] = v4;
    }
  }
}

// ---------------------------------------------------------------- kernel E
// Exact tag logit from fragment-major Wob (same bf16 values as pz path).
__global__ __launch_bounds__(256) void tag_kernel(
    const ushort* __restrict__ featb, const ushort* __restrict__ Wob,
    const float* __restrict__ bo, const int* __restrict__ tags,
    float* __restrict__ tagl) {
  int l = blockIdx.x * 4 + (threadIdx.x >> 6);
  int lane = threadIdx.x & 63;
  int tg = tags[l];
  int c = tg >> 7, nt = (tg >> 4) & 7, lr = tg & 15;
  int k0 = lane << 2;
  int kh = k0 >> 7, k4 = (k0 >> 5) & 3, lq = (k0 >> 3) & 3, e = k0 & 7;
  size_t f = ((((size_t)c * 2 + kh) * 4 + k4) * 8 + nt) * 64 + lq * 16 + lr;
  ushort4 wa = *(const ushort4*)&Wob[f * 8 + e];
  ushort4 fa = *(const ushort4*)&featb[(size_t)l * 256 + k0];
  float s = bf2f(fa.x) * bf2f(wa.x) + bf2f(fa.y) * bf2f(wa.y) +
            bf2f(fa.z) * bf2f(wa.z) + bf2f(fa.w) * bf2f(wa.w);
  #pragma unroll
  for (int off = 1; off < 64; off <<= 1) s += __shfl_xor(s, off);
  if (lane == 0) tagl[l] = s + bo[tg];
}

// ---------------------------------------------------------------- kernel F
__global__ __launch_bounds__(256) void reduce_kernel(
    const float* __restrict__ pz, const float* __restrict__ tagl,
    float* __restrict__ out) {
  int l = blockIdx.x * 256 + threadIdx.x;
  float z = 0.f;
  for (int c = 0; c < 2 * NCH; ++c) z += pz[(size_t)c * L + l];
  float per = logf(z) - tagl[l];
  float v = per * (1.0f / (4096.0f + 1e-5f));
  #pragma unroll
  for (int off = 1; off < 64; off <<= 1) v += __shfl_xor(v, off);
  __shared__ float wsum[4];
  if ((threadIdx.x & 63) == 0) wsum[threadIdx.x >> 6] = v;
  __syncthreads();
  if (threadIdx.x == 0)
    atomicAdd(out, wsum[0] + wsum[1] + wsum[2] + wsum[3]);
}

// ---------------------------------------------------------------- launch
extern "C" void kernel_launch(void* const* d_in, const int* in_sizes, int n_in,
                              void* d_out, int out_size, void* d_ws,
                              size_t ws_size, hipStream_t stream) {
  const float* hidden = (const float*)d_in[0];
  const int* begins = (const int*)d_in[1];
  const int* ends = (const int*)d_in[2];
  const int* bids = (const int*)d_in[3];
  const int* tags = (const int*)d_in[4];
  const float* W1 = (const float*)d_in[5];
  const float* b1 = (const float*)d_in[6];
  const float* W2 = (const float*)d_in[7];
  const float* b2 = (const float*)d_in[8];
  const float* Wo = (const float*)d_in[9];
  const float* bo = (const float*)d_in[10];
  float* out = (float*)d_out;

  ushort* featb = (ushort*)d_ws;                       // L*256
  ushort* Wob = featb + (size_t)L * 256;               // V*256 (frag-major)
  ushort* spanb = Wob + (size_t)V * 256;               // L*1536
  ushort* W1b = spanb + (size_t)L * 1536;              // 256*1536
  ushort* W2b = W1b + (size_t)256 * 1536;              // 256*256
  // pz (2*NCH*L f32 = 8.2 MB) aliases spanb (12.6 MB): spanb dead after
  // feat_mfma_kernel; logits2 runs strictly after it in-stream.
  float* pz = (float*)spanb;
  float* tagl = (float*)(W2b + (size_t)256 * 256);     // L

  hipMemsetAsync(d_out, 0, sizeof(float), stream);
  spanb_kernel<<<L / 2, 256, 0, stream>>>(hidden, begins, ends, bids, spanb);
  tcast_kernel<<<dim3(4, 24), 256, 0, stream>>>(W1, W1b, 1536, LAB);
  tcast_kernel<<<dim3(4, 4), 256, 0, stream>>>(W2, W2b, LAB, LAB);
  tcast_wo_kernel<<<dim3(500, 4), 256, 0, stream>>>(Wo, Wob);
  feat_mfma_kernel<<<128, 256, 0, stream>>>(spanb, W1b, b1, W2b, b2, featb);
  logits2_kernel<<<dim3(16, NCH), 256, 0, stream>>>(featb, Wob, bo, pz);
  tag_kernel<<<L / 4, 256, 0, stream>>>(featb, Wob, bo, tags, tagl);
  reduce_kernel<<<L / 256, 256, 0, stream>>>(pz, tagl, out);
}

// Round 5
// 289.709 us; speedup vs baseline: 1.2195x; 1.2195x over previous
//
#include <hip/hip_runtime.h>
#include <math.h>

#define S 2048
#define B 16
#define H 512
#define L 4096
#define SMAX 16
#define LAB 256
#define V 32000
#define NCH 250          // V / 128 vocab chunks
#define LOG2E 1.44269504f

typedef __attribute__((ext_vector_type(8))) short short8;
typedef __attribute__((ext_vector_type(4))) float float4v;

__device__ inline ushort f2bf(float x) {
  union { float f; unsigned u; } c; c.f = x;
  unsigned r = c.u + 0x7fffu + ((c.u >> 16) & 1u);
  return (ushort)(r >> 16);
}
__device__ inline float bf2f(ushort h) {
  union { unsigned u; float f; } c; c.u = ((unsigned)h) << 16;
  return c.f;
}

// ---------------------------------------------------------------- kernel A
// span gather -> spanb bf16 [L][1536] = concat(left, mean, right)
__global__ __launch_bounds__(256) void spanb_kernel(
    const float* __restrict__ hidden, const int* __restrict__ begins,
    const int* __restrict__ ends, const int* __restrict__ bids,
    ushort* __restrict__ spanb) {
  int sub = threadIdx.x >> 7, t = threadIdx.x & 127;
  int l = blockIdx.x * 2 + sub;
  int b = bids[l], s0 = begins[l], s1 = ends[l];
  const float4* hidv = (const float4*)hidden;
  float4 lf = hidv[((size_t)(s0 - 1) * B + b) * 128 + t];
  float4 rf = hidv[((size_t)s1 * B + b) * 128 + t];
  float4 m = make_float4(0.f, 0.f, 0.f, 0.f);
  int len = s1 - s0;
  for (int j = 0; j < len; ++j) {
    float4 g = hidv[((size_t)(s0 + j) * B + b) * 128 + t];
    m.x += g.x; m.y += g.y; m.z += g.z; m.w += g.w;
  }
  float inv = 1.0f / (float)len;
  ushort* sp = spanb + (size_t)l * 1536;
  ushort4 u;
  u.x = f2bf(lf.x); u.y = f2bf(lf.y); u.z = f2bf(lf.z); u.w = f2bf(lf.w);
  *(ushort4*)&sp[t * 4] = u;
  u.x = f2bf(m.x * inv); u.y = f2bf(m.y * inv);
  u.z = f2bf(m.z * inv); u.w = f2bf(m.w * inv);
  *(ushort4*)&sp[512 + t * 4] = u;
  u.x = f2bf(rf.x); u.y = f2bf(rf.y); u.z = f2bf(rf.z); u.w = f2bf(rf.w);
  *(ushort4*)&sp[1024 + t * 4] = u;
}

// ---------------------------------------------------------------- kernel B
// generic transpose+cast: src[K][N] f32 -> dst[N][K] bf16 (W1, W2)
__global__ __launch_bounds__(256) void tcast_kernel(
    const float* __restrict__ src, ushort* __restrict__ dst, int K, int N) {
  __shared__ ushort tile[64 * 72];
  int t = threadIdx.x;
  int n0 = blockIdx.x * 64;
  int k0 = blockIdx.y * 64;
  #pragma unroll
  for (int p = 0; p < 16; ++p) {
    int k = p * 4 + (t >> 6);
    int n = t & 63;
    tile[n * 72 + k] = f2bf(src[(size_t)(k0 + k) * N + n0 + n]);
  }
  __syncthreads();
  #pragma unroll
  for (int p = 0; p < 2; ++p) {
    int idx = p * 256 + t;
    int n = idx >> 3, c = idx & 7;
    *(uint4*)&dst[(size_t)(n0 + n) * K + k0 + c * 8] =
        *(const uint4*)&tile[n * 72 + c * 8];
  }
}

// ---------------------------------------------------------------- kernel B2
// Wo [256][32000] f32 -> fragment-major bf16 Wob:
//   frag f = (((c*2+kh)*4 + k4)*8 + nt)*64 + lq*16 + lr, 8 ushorts each,
//   where v = c*128 + nt*16 + lr, k = kh*128 + k4*32 + lq*8 + e.
__global__ __launch_bounds__(256) void tcast_wo_kernel(
    const float* __restrict__ src, ushort* __restrict__ dst) {
  __shared__ ushort tile[64 * 72];
  int t = threadIdx.x;
  int n0 = blockIdx.x * 64;            // vocab
  int k0 = blockIdx.y * 64;            // K
  #pragma unroll
  for (int p = 0; p < 16; ++p) {
    int k = p * 4 + (t >> 6);
    int n = t & 63;
    tile[n * 72 + k] = f2bf(src[(size_t)(k0 + k) * V + n0 + n]);
  }
  __syncthreads();
  #pragma unroll
  for (int p = 0; p < 2; ++p) {
    int idx = p * 256 + t;             // 512 uint4 per tile
    int n = idx >> 3, c8 = idx & 7;
    int v = n0 + n, k = k0 + c8 * 8;
    int c = v >> 7, nt = (v >> 4) & 7, lr = v & 15;
    int kh = k >> 7, k4 = (k >> 5) & 3, lq = (k >> 3) & 3;
    size_t f = ((((size_t)c * 2 + kh) * 4 + k4) * 8 + nt) * 64 + lq * 16 + lr;
    *(uint4*)&dst[f * 8] = *(const uint4*)&tile[n * 72 + c8 * 8];
  }
}

// ---------------------------------------------------------------- kernel C
// MFMA MLP: featb = bf16( sigmoid(spanb@W1+b1) @ W2 + b2 )
// REWORKED: old version had 128 blocks x 58KB LDS -> 2 blocks/CU -> only
// 64 of 256 CUs busy. Now 256 blocks x 16 labels, NO A/B LDS staging:
// A-frags (spanb) and B-frags (W1b/W2b rows) are 16B-contiguous in global
// and L2-resident -> read direct (round-0/3 proven pattern). LDS only for
// the H transpose (8.4 KB). One barrier total. High occupancy, all CUs.
__global__ __launch_bounds__(256) void feat_mfma_kernel(
    const ushort* __restrict__ spanb, const ushort* __restrict__ W1b,
    const float* __restrict__ b1, const ushort* __restrict__ W2b,
    const float* __restrict__ b2, ushort* __restrict__ featb) {
  __shared__ ushort Hs[16 * 264];
  int tid = threadIdx.x;
  int w = tid >> 6, lane = tid & 63;
  int lr = lane & 15, lq = lane >> 4;
  int l0 = blockIdx.x * 16;

  // GEMM1: acc[nt] over cols w*64+nt*16+lr, rows l0+lr (mt=1), K=1536
  // k-step stride = 32 ushorts = 4 short8; full-unroll -> imm offsets
  const short8* arow = (const short8*)(spanb + (size_t)(l0 + lr) * 1536 + lq * 8);
  const short8* brow[4];
  #pragma unroll
  for (int nt = 0; nt < 4; ++nt)
    brow[nt] = (const short8*)(W1b + (size_t)(w * 64 + nt * 16 + lr) * 1536 + lq * 8);

  float4v acc[4];
  float4v zero = {0.f, 0.f, 0.f, 0.f};
  #pragma unroll
  for (int nt = 0; nt < 4; ++nt) acc[nt] = zero;

  short8 af[2], bf[2][4];
  af[0] = arow[0];
  #pragma unroll
  for (int nt = 0; nt < 4; ++nt) bf[0][nt] = brow[nt][0];

  #pragma unroll
  for (int s = 0; s < 48; ++s) {
    int cur = s & 1, nxt = cur ^ 1;
    if (s < 47) {
      af[nxt] = arow[(s + 1) * 4];
      #pragma unroll
      for (int nt = 0; nt < 4; ++nt) bf[nxt][nt] = brow[nt][(s + 1) * 4];
    }
    #pragma unroll
    for (int nt = 0; nt < 4; ++nt)
      acc[nt] = __builtin_amdgcn_mfma_f32_16x16x32_bf16(
          af[cur], bf[cur][nt], acc[nt], 0, 0, 0);
  }

  // sigmoid + bias -> Hs (C-layout row = lq*4+r, col = w*64+nt*16+lr)
  {
    #pragma unroll
    for (int nt = 0; nt < 4; ++nt) {
      float b1v = b1[w * 64 + nt * 16 + lr];
      #pragma unroll
      for (int r = 0; r < 4; ++r) {
        int row = lq * 4 + r;
        float h = 1.0f / (1.0f + __expf(-(acc[nt][r] + b1v)));
        Hs[row * 264 + w * 64 + nt * 16 + lr] = f2bf(h);
      }
    }
  }
  __syncthreads();

  // GEMM2: A = Hs (LDS), B = W2b rows direct from global (131KB, L2-hot)
  const short8* wrow[4];
  #pragma unroll
  for (int nt = 0; nt < 4; ++nt)
    wrow[nt] = (const short8*)(W2b + (size_t)(w * 64 + nt * 16 + lr) * 256 + lq * 8);

  float4v acc2[4];
  #pragma unroll
  for (int nt = 0; nt < 4; ++nt) acc2[nt] = zero;

  short8 bf2[2][4];
  #pragma unroll
  for (int nt = 0; nt < 4; ++nt) bf2[0][nt] = wrow[nt][0];

  #pragma unroll
  for (int s = 0; s < 8; ++s) {
    int cur = s & 1, nxt = cur ^ 1;
    if (s < 7) {
      #pragma unroll
      for (int nt = 0; nt < 4; ++nt) bf2[nxt][nt] = wrow[nt][(s + 1) * 4];
    }
    short8 af2 = *(const short8*)&Hs[lr * 264 + s * 32 + lq * 8];
    #pragma unroll
    for (int nt = 0; nt < 4; ++nt)
      acc2[nt] = __builtin_amdgcn_mfma_f32_16x16x32_bf16(
          af2, bf2[cur][nt], acc2[nt], 0, 0, 0);
  }

  {
    #pragma unroll
    for (int nt = 0; nt < 4; ++nt) {
      float b2v = b2[w * 64 + nt * 16 + lr];
      #pragma unroll
      for (int r = 0; r < 4; ++r) {
        int row = lq * 4 + r;
        int col = w * 64 + nt * 16 + lr;
        featb[(size_t)(l0 + row) * 256 + col] = f2bf(acc2[nt][r] + b2v);
      }
    }
  }
}

// ---------------------------------------------------------------- kernel D
// logits + sumexp partials. EXACTLY the round-3 103.5us kernel, plus the
// occupancy fix: unified regfile on gfx950 counts arch VGPR + AGPR (acc)
// together. R3 was 72+64=136 -> 3 waves/SIMD. Moving the bov load into the
// epilogue drops in-loop arch to ~64 -> 64+64=128 -> 4 waves/SIMD with
// launch_bounds(256,4). LDS 32KB allows 5 blocks/CU; reg-bound at 4.
__global__ __launch_bounds__(256, 4) void logits2_kernel(
    const ushort* __restrict__ featb, const ushort* __restrict__ Wob,
    const float* __restrict__ bo, float* __restrict__ pz) {
  __shared__ ushort Blds[16384];         // 32 KB: one K-half, fragment-major
  int tid = threadIdx.x;
  int w = tid >> 6, lane = tid & 63;
  int lr = lane & 15, lq = lane >> 4;
  int l0 = blockIdx.x * 128;
  int v0 = blockIdx.y * 128;

  // per-mt global A pointers; k-step advance = 32 ushorts = 4 short8
  const short8* aptr[2];
  #pragma unroll
  for (int mt = 0; mt < 2; ++mt)
    aptr[mt] = (const short8*)(featb +
        (size_t)(l0 + w * 32 + mt * 16 + lr) * 256 + lq * 8);

  float4v acc[2][8];
  float4v zero = {0.f, 0.f, 0.f, 0.f};
  #pragma unroll
  for (int mt = 0; mt < 2; ++mt)
    #pragma unroll
    for (int nt = 0; nt < 8; ++nt) acc[mt][nt] = zero;

  short8 af[2][2];
  #pragma unroll
  for (int mt = 0; mt < 2; ++mt) af[0][mt] = aptr[mt][0];

  #pragma unroll
  for (int kh = 0; kh < 2; ++kh) {
    // stage K-half kh: 2048 frags, pure linear copy, async to LDS
    {
      const uint4* src4 = (const uint4*)(Wob +
          (size_t)blockIdx.y * 32768 + (size_t)kh * 16384);
      #pragma unroll
      for (int p = 0; p < 8; ++p) {
        int idx = p * 256 + tid;
        __builtin_amdgcn_global_load_lds(
            (const __attribute__((address_space(1))) unsigned int*)(src4 + idx),
            (__attribute__((address_space(3))) unsigned int*)&Blds[(size_t)idx * 8],
            16, 0, 0);
      }
    }
    __syncthreads();                     // drains the LDS-DMA
    #pragma unroll
    for (int k4 = 0; k4 < 4; ++k4) {
      int kg = kh * 4 + k4;
      int cur = kg & 1, nxt = cur ^ 1;
      if (kg < 7) {
        #pragma unroll
        for (int mt = 0; mt < 2; ++mt)
          af[nxt][mt] = aptr[mt][(kg + 1) * 4];
      }
      short8 bf[8];
      #pragma unroll
      for (int nt = 0; nt < 8; ++nt)
        bf[nt] = *(const short8*)&Blds[(size_t)(((k4 * 8 + nt) * 64) + lane) * 8];
      __builtin_amdgcn_s_setprio(1);
      #pragma unroll
      for (int mt = 0; mt < 2; ++mt)
        #pragma unroll
        for (int nt = 0; nt < 8; ++nt)
          acc[mt][nt] = __builtin_amdgcn_mfma_f32_16x16x32_bf16(
              af[cur][mt], bf[nt], acc[mt][nt], 0, 0, 0);
      __builtin_amdgcn_s_setprio(0);
    }
    if (kh == 0) __syncthreads();        // protect Blds before restage
  }

  // epilogue: z[row] = sum_cols exp(logit + bo), no max (logits bounded)
  // bov loaded HERE (not before the k-loop) to keep in-loop arch regs <=64
  float bov[8];
  #pragma unroll
  for (int nt = 0; nt < 8; ++nt)
    bov[nt] = bo[v0 + nt * 16 + lr] * LOG2E;
  float z[2][4];
  #pragma unroll
  for (int mt = 0; mt < 2; ++mt)
    #pragma unroll
    for (int r = 0; r < 4; ++r) z[mt][r] = 0.f;
  #pragma unroll
  for (int mt = 0; mt < 2; ++mt)
    #pragma unroll
    for (int nt = 0; nt < 8; ++nt)
      #pragma unroll
      for (int r = 0; r < 4; ++r)
        z[mt][r] += exp2f(fmaf(acc[mt][nt][r], LOG2E, bov[nt]));
  #pragma unroll
  for (int mt = 0; mt < 2; ++mt)
    #pragma unroll
    for (int r = 0; r < 4; ++r) {
      #pragma unroll
      for (int off = 1; off < 16; off <<= 1)
        z[mt][r] += __shfl_xor(z[mt][r], off);
    }
  if (lr == 0) {
    int ch = blockIdx.y;
    #pragma unroll
    for (int mt = 0; mt < 2; ++mt) {
      float4 v4;
      v4.x = z[mt][0]; v4.y = z[mt][1]; v4.z = z[mt][2]; v4.w = z[mt][3];
      *(float4*)&pz[(size_t)ch * L + l0 + w * 32 + mt * 16 + lq * 4] = v4;
    }
  }
}

// ---------------------------------------------------------------- kernel E
// Exact tag logit from fragment-major Wob (same bf16 values as pz path).
__global__ __launch_bounds__(256) void tag_kernel(
    const ushort* __restrict__ featb, const ushort* __restrict__ Wob,
    const float* __restrict__ bo, const int* __restrict__ tags,
    float* __restrict__ tagl) {
  int l = blockIdx.x * 4 + (threadIdx.x >> 6);
  int lane = threadIdx.x & 63;
  int tg = tags[l];
  int c = tg >> 7, nt = (tg >> 4) & 7, lr = tg & 15;
  int k0 = lane << 2;
  int kh = k0 >> 7, k4 = (k0 >> 5) & 3, lq = (k0 >> 3) & 3, e = k0 & 7;
  size_t f = ((((size_t)c * 2 + kh) * 4 + k4) * 8 + nt) * 64 + lq * 16 + lr;
  ushort4 wa = *(const ushort4*)&Wob[f * 8 + e];
  ushort4 fa = *(const ushort4*)&featb[(size_t)l * 256 + k0];
  float s = bf2f(fa.x) * bf2f(wa.x) + bf2f(fa.y) * bf2f(wa.y) +
            bf2f(fa.z) * bf2f(wa.z) + bf2f(fa.w) * bf2f(wa.w);
  #pragma unroll
  for (int off = 1; off < 64; off <<= 1) s += __shfl_xor(s, off);
  if (lane == 0) tagl[l] = s + bo[tg];
}

// ---------------------------------------------------------------- kernel F
__global__ __launch_bounds__(256) void reduce_kernel(
    const float* __restrict__ pz, const float* __restrict__ tagl,
    float* __restrict__ out) {
  int l = blockIdx.x * 256 + threadIdx.x;
  float z = 0.f;
  for (int c = 0; c < NCH; ++c) z += pz[(size_t)c * L + l];
  float per = logf(z) - tagl[l];
  float v = per * (1.0f / (4096.0f + 1e-5f));
  #pragma unroll
  for (int off = 1; off < 64; off <<= 1) v += __shfl_xor(v, off);
  __shared__ float wsum[4];
  if ((threadIdx.x & 63) == 0) wsum[threadIdx.x >> 6] = v;
  __syncthreads();
  if (threadIdx.x == 0)
    atomicAdd(out, wsum[0] + wsum[1] + wsum[2] + wsum[3]);
}

// ---------------------------------------------------------------- launch
extern "C" void kernel_launch(void* const* d_in, const int* in_sizes, int n_in,
                              void* d_out, int out_size, void* d_ws,
                              size_t ws_size, hipStream_t stream) {
  const float* hidden = (const float*)d_in[0];
  const int* begins = (const int*)d_in[1];
  const int* ends = (const int*)d_in[2];
  const int* bids = (const int*)d_in[3];
  const int* tags = (const int*)d_in[4];
  const float* W1 = (const float*)d_in[5];
  const float* b1 = (const float*)d_in[6];
  const float* W2 = (const float*)d_in[7];
  const float* b2 = (const float*)d_in[8];
  const float* Wo = (const float*)d_in[9];
  const float* bo = (const float*)d_in[10];
  float* out = (float*)d_out;

  ushort* featb = (ushort*)d_ws;                       // L*256
  ushort* Wob = featb + (size_t)L * 256;               // V*256 (frag-major)
  ushort* spanb = Wob + (size_t)V * 256;               // L*1536
  ushort* W1b = spanb + (size_t)L * 1536;              // 256*1536
  ushort* W2b = W1b + (size_t)256 * 1536;              // 256*256
  // pz (NCH*L f32 = 4.1 MB) aliases spanb (12.6 MB): spanb dead after
  // feat_mfma_kernel; logits2 runs strictly after it in-stream.
  float* pz = (float*)spanb;
  float* tagl = (float*)(W2b + (size_t)256 * 256);     // L

  hipMemsetAsync(d_out, 0, sizeof(float), stream);
  spanb_kernel<<<L / 2, 256, 0, stream>>>(hidden, begins, ends, bids, spanb);
  tcast_kernel<<<dim3(4, 24), 256, 0, stream>>>(W1, W1b, 1536, LAB);
  tcast_kernel<<<dim3(4, 4), 256, 0, stream>>>(W2, W2b, LAB, LAB);
  tcast_wo_kernel<<<dim3(500, 4), 256, 0, stream>>>(Wo, Wob);
  feat_mfma_kernel<<<256, 256, 0, stream>>>(spanb, W1b, b1, W2b, b2, featb);
  logits2_kernel<<<dim3(32, NCH), 256, 0, stream>>>(featb, Wob, bo, pz);
  tag_kernel<<<L / 4, 256, 0, stream>>>(featb, Wob, bo, tags, tagl);
  reduce_kernel<<<L / 256, 256, 0, stream>>>(pz, tagl, out);
}

// Round 6
// 287.508 us; speedup vs baseline: 1.2288x; 1.0077x over previous
//
#include <hip/hip_runtime.h>
#include <math.h>

#define S 2048
#define B 16
#define H 512
#define L 4096
#define SMAX 16
#define LAB 256
#define V 32000
#define NCH 250          // V / 128 vocab chunks
#define LOG2E 1.44269504f

typedef __attribute__((ext_vector_type(8))) short short8;
typedef __attribute__((ext_vector_type(4))) float float4v;

__device__ inline ushort f2bf(float x) {
  union { float f; unsigned u; } c; c.f = x;
  unsigned r = c.u + 0x7fffu + ((c.u >> 16) & 1u);
  return (ushort)(r >> 16);
}
__device__ inline float bf2f(ushort h) {
  union { unsigned u; float f; } c; c.u = ((unsigned)h) << 16;
  return c.f;
}

// ---------------------------------------------------------------- kernel P
// Fused prep: blocks [0,2048) span gather; [2048,2144) W1 tcast;
// [2144,2160) W2 tcast; [2160,4160) Wo frag-major tcast.
// All sub-jobs independent; fusion cuts 3 launches (~14us fixed cost each).
__global__ __launch_bounds__(256) void prep_kernel(
    const float* __restrict__ hidden, const int* __restrict__ begins,
    const int* __restrict__ ends, const int* __restrict__ bids,
    ushort* __restrict__ spanb, const float* __restrict__ W1,
    ushort* __restrict__ W1b, const float* __restrict__ W2,
    ushort* __restrict__ W2b, const float* __restrict__ Wo,
    ushort* __restrict__ Wob) {
  __shared__ ushort tile[64 * 72];
  int bid = blockIdx.x;
  int t = threadIdx.x;

  if (bid < 2048) {                      // ---- span gather
    int sub = t >> 7, tt = t & 127;
    int l = bid * 2 + sub;
    int b = bids[l], s0 = begins[l], s1 = ends[l];
    const float4* hidv = (const float4*)hidden;
    float4 lf = hidv[((size_t)(s0 - 1) * B + b) * 128 + tt];
    float4 rf = hidv[((size_t)s1 * B + b) * 128 + tt];
    float4 m = make_float4(0.f, 0.f, 0.f, 0.f);
    int len = s1 - s0;
    for (int j = 0; j < len; ++j) {
      float4 g = hidv[((size_t)(s0 + j) * B + b) * 128 + tt];
      m.x += g.x; m.y += g.y; m.z += g.z; m.w += g.w;
    }
    float inv = 1.0f / (float)len;
    ushort* sp = spanb + (size_t)l * 1536;
    ushort4 u;
    u.x = f2bf(lf.x); u.y = f2bf(lf.y); u.z = f2bf(lf.z); u.w = f2bf(lf.w);
    *(ushort4*)&sp[tt * 4] = u;
    u.x = f2bf(m.x * inv); u.y = f2bf(m.y * inv);
    u.z = f2bf(m.z * inv); u.w = f2bf(m.w * inv);
    *(ushort4*)&sp[512 + tt * 4] = u;
    u.x = f2bf(rf.x); u.y = f2bf(rf.y); u.z = f2bf(rf.z); u.w = f2bf(rf.w);
    *(ushort4*)&sp[1024 + tt * 4] = u;
    return;
  }

  // ---- transpose+cast tiles
  const float* src; ushort* dst; int K, N, n0, k0; bool wo = false;
  if (bid < 2144) {
    int u = bid - 2048; src = W1; dst = W1b; K = 1536; N = 256;
    n0 = (u & 3) * 64; k0 = (u >> 2) * 64;
  } else if (bid < 2160) {
    int u = bid - 2144; src = W2; dst = W2b; K = 256; N = 256;
    n0 = (u & 3) * 64; k0 = (u >> 2) * 64;
  } else {
    int u = bid - 2160; src = Wo; dst = Wob; K = 256; N = V;
    n0 = (u % 500) * 64; k0 = (u / 500) * 64; wo = true;
  }
  #pragma unroll
  for (int p = 0; p < 16; ++p) {
    int k = p * 4 + (t >> 6);
    int n = t & 63;
    tile[n * 72 + k] = f2bf(src[(size_t)(k0 + k) * N + n0 + n]);
  }
  __syncthreads();
  if (!wo) {
    #pragma unroll
    for (int p = 0; p < 2; ++p) {
      int idx = p * 256 + t;
      int n = idx >> 3, c = idx & 7;
      *(uint4*)&dst[(size_t)(n0 + n) * K + k0 + c * 8] =
          *(const uint4*)&tile[n * 72 + c * 8];
    }
  } else {
    // fragment-major: f = (((c*2+kh)*4+k4)*8+nt)*64 + lq*16 + lr
    #pragma unroll
    for (int p = 0; p < 2; ++p) {
      int idx = p * 256 + t;
      int n = idx >> 3, c8 = idx & 7;
      int v = n0 + n, k = k0 + c8 * 8;
      int c = v >> 7, nt = (v >> 4) & 7, lr = v & 15;
      int kh = k >> 7, k4 = (k >> 5) & 3, lq = (k >> 3) & 3;
      size_t f = ((((size_t)c * 2 + kh) * 4 + k4) * 8 + nt) * 64 + lq * 16 + lr;
      *(uint4*)&dst[f * 8] = *(const uint4*)&tile[n * 72 + c8 * 8];
    }
  }
}

// ---------------------------------------------------------------- kernel C
// MFMA MLP: featb = bf16( sigmoid(spanb@W1+b1) @ W2 + b2 )
// 256 blocks x 16 labels, A/B direct from global (L2-hot), LDS only for
// the H transpose. Also zeroes `out` (replaces the memset launch).
__global__ __launch_bounds__(256) void feat_mfma_kernel(
    const ushort* __restrict__ spanb, const ushort* __restrict__ W1b,
    const float* __restrict__ b1, const ushort* __restrict__ W2b,
    const float* __restrict__ b2, ushort* __restrict__ featb,
    float* __restrict__ out) {
  __shared__ ushort Hs[16 * 264];
  int tid = threadIdx.x;
  if (blockIdx.x == 0 && tid == 0) *out = 0.f;   // zero accumulator output
  int w = tid >> 6, lane = tid & 63;
  int lr = lane & 15, lq = lane >> 4;
  int l0 = blockIdx.x * 16;

  const short8* arow = (const short8*)(spanb + (size_t)(l0 + lr) * 1536 + lq * 8);
  const short8* brow[4];
  #pragma unroll
  for (int nt = 0; nt < 4; ++nt)
    brow[nt] = (const short8*)(W1b + (size_t)(w * 64 + nt * 16 + lr) * 1536 + lq * 8);

  float4v acc[4];
  float4v zero = {0.f, 0.f, 0.f, 0.f};
  #pragma unroll
  for (int nt = 0; nt < 4; ++nt) acc[nt] = zero;

  short8 af[2], bf[2][4];
  af[0] = arow[0];
  #pragma unroll
  for (int nt = 0; nt < 4; ++nt) bf[0][nt] = brow[nt][0];

  #pragma unroll
  for (int s = 0; s < 48; ++s) {
    int cur = s & 1, nxt = cur ^ 1;
    if (s < 47) {
      af[nxt] = arow[(s + 1) * 4];
      #pragma unroll
      for (int nt = 0; nt < 4; ++nt) bf[nxt][nt] = brow[nt][(s + 1) * 4];
    }
    #pragma unroll
    for (int nt = 0; nt < 4; ++nt)
      acc[nt] = __builtin_amdgcn_mfma_f32_16x16x32_bf16(
          af[cur], bf[cur][nt], acc[nt], 0, 0, 0);
  }

  {
    #pragma unroll
    for (int nt = 0; nt < 4; ++nt) {
      float b1v = b1[w * 64 + nt * 16 + lr];
      #pragma unroll
      for (int r = 0; r < 4; ++r) {
        int row = lq * 4 + r;
        float h = 1.0f / (1.0f + __expf(-(acc[nt][r] + b1v)));
        Hs[row * 264 + w * 64 + nt * 16 + lr] = f2bf(h);
      }
    }
  }
  __syncthreads();

  const short8* wrow[4];
  #pragma unroll
  for (int nt = 0; nt < 4; ++nt)
    wrow[nt] = (const short8*)(W2b + (size_t)(w * 64 + nt * 16 + lr) * 256 + lq * 8);

  float4v acc2[4];
  #pragma unroll
  for (int nt = 0; nt < 4; ++nt) acc2[nt] = zero;

  short8 bf2[2][4];
  #pragma unroll
  for (int nt = 0; nt < 4; ++nt) bf2[0][nt] = wrow[nt][0];

  #pragma unroll
  for (int s = 0; s < 8; ++s) {
    int cur = s & 1, nxt = cur ^ 1;
    if (s < 7) {
      #pragma unroll
      for (int nt = 0; nt < 4; ++nt) bf2[nxt][nt] = wrow[nt][(s + 1) * 4];
    }
    short8 af2 = *(const short8*)&Hs[lr * 264 + s * 32 + lq * 8];
    #pragma unroll
    for (int nt = 0; nt < 4; ++nt)
      acc2[nt] = __builtin_amdgcn_mfma_f32_16x16x32_bf16(
          af2, bf2[cur][nt], acc2[nt], 0, 0, 0);
  }

  {
    #pragma unroll
    for (int nt = 0; nt < 4; ++nt) {
      float b2v = b2[w * 64 + nt * 16 + lr];
      #pragma unroll
      for (int r = 0; r < 4; ++r) {
        int row = lq * 4 + r;
        int col = w * 64 + nt * 16 + lr;
        featb[(size_t)(l0 + row) * 256 + col] = f2bf(acc2[nt][r] + b2v);
      }
    }
  }
}

// ---------------------------------------------------------------- kernel D
// Fused logits(+tag). Blocks [0,4000): 2 vocab chunks each (grid 32x125,
// label-block fastest -> round-0 co-schedule preserved). The c1 first-half
// stage DMA is ISSUED before c0's epilogue: the ~700cyc exp/shuffle tail
// hides the stage latency (bov/af loaded before the DMA issues so their
// vmcnt wait doesn't drain it). Blocks [4000,5024): exact tag logits.
// Launch count for the whole pipeline: 9 -> 4.
__global__ __launch_bounds__(256, 4) void logits_kernel(
    const ushort* __restrict__ featb, const ushort* __restrict__ Wob,
    const float* __restrict__ bo, const int* __restrict__ tags,
    float* __restrict__ pz, float* __restrict__ tagl) {
  __shared__ ushort Blds[16384];         // 32 KB: one K-half, fragment-major
  int bid = blockIdx.x;
  int tid = threadIdx.x;
  int lane = tid & 63;
  int lr = lane & 15, lq = lane >> 4;

  if (bid >= 4000) {                     // ---- tag path
    int l = (bid - 4000) * 4 + (tid >> 6);
    int tg = tags[l];
    int c = tg >> 7, nt = (tg >> 4) & 7, tlr = tg & 15;
    int k0 = lane << 2;
    int kh = k0 >> 7, k4 = (k0 >> 5) & 3, tlq = (k0 >> 3) & 3, e = k0 & 7;
    size_t f = ((((size_t)c * 2 + kh) * 4 + k4) * 8 + nt) * 64 + tlq * 16 + tlr;
    ushort4 wa = *(const ushort4*)&Wob[f * 8 + e];
    ushort4 fa = *(const ushort4*)&featb[(size_t)l * 256 + k0];
    float s = bf2f(fa.x) * bf2f(wa.x) + bf2f(fa.y) * bf2f(wa.y) +
              bf2f(fa.z) * bf2f(wa.z) + bf2f(fa.w) * bf2f(wa.w);
    #pragma unroll
    for (int off = 1; off < 64; off <<= 1) s += __shfl_xor(s, off);
    if (lane == 0) tagl[l] = s + bo[tg];
    return;
  }

  int w = tid >> 6;
  int lb = bid & 31;
  int cpair = bid >> 5;
  int c0 = cpair * 2, c1 = c0 + 1;
  int l0 = lb * 128;

  const short8* aptr[2];
  #pragma unroll
  for (int mt = 0; mt < 2; ++mt)
    aptr[mt] = (const short8*)(featb +
        (size_t)(l0 + w * 32 + mt * 16 + lr) * 256 + lq * 8);

  float4v acc[2][8];
  float4v zero = {0.f, 0.f, 0.f, 0.f};
  #pragma unroll
  for (int mt = 0; mt < 2; ++mt)
    #pragma unroll
    for (int nt = 0; nt < 8; ++nt) acc[mt][nt] = zero;

  short8 af[2][2];
  #pragma unroll
  for (int mt = 0; mt < 2; ++mt) af[0][mt] = aptr[mt][0];

#define STAGE_HALF(ch, kh)                                                    \
  {                                                                           \
    const uint4* src4 = (const uint4*)(Wob +                                  \
        (size_t)(ch) * 32768 + (size_t)(kh) * 16384);                         \
    _Pragma("unroll")                                                         \
    for (int p = 0; p < 8; ++p) {                                             \
      int idx = p * 256 + tid;                                                \
      __builtin_amdgcn_global_load_lds(                                       \
          (const __attribute__((address_space(1))) unsigned int*)(src4 + idx),\
          (__attribute__((address_space(3))) unsigned int*)&Blds[(size_t)idx * 8], \
          16, 0, 0);                                                          \
    }                                                                         \
  }

#define KG_BLOCK(kh)                                                          \
  _Pragma("unroll")                                                           \
  for (int k4 = 0; k4 < 4; ++k4) {                                            \
    int kg = (kh) * 4 + k4;                                                   \
    int cur = kg & 1, nxt = cur ^ 1;                                          \
    if (kg < 7) {                                                             \
      _Pragma("unroll")                                                       \
      for (int mt = 0; mt < 2; ++mt)                                          \
        af[nxt][mt] = aptr[mt][(kg + 1) * 4];                                 \
    }                                                                         \
    short8 bf[8];                                                             \
    _Pragma("unroll")                                                         \
    for (int nt = 0; nt < 8; ++nt)                                            \
      bf[nt] = *(const short8*)&Blds[(size_t)(((k4 * 8 + nt) * 64) + lane) * 8]; \
    __builtin_amdgcn_s_setprio(1);                                            \
    _Pragma("unroll")                                                         \
    for (int mt = 0; mt < 2; ++mt)                                            \
      _Pragma("unroll")                                                       \
      for (int nt = 0; nt < 8; ++nt)                                          \
        acc[mt][nt] = __builtin_amdgcn_mfma_f32_16x16x32_bf16(                \
            af[cur][mt], bf[nt], acc[mt][nt], 0, 0, 0);                       \
    __builtin_amdgcn_s_setprio(0);                                            \
  }

#define EPILOGUE(ch)                                                          \
  {                                                                           \
    float z[2][4];                                                            \
    _Pragma("unroll")                                                         \
    for (int mt = 0; mt < 2; ++mt)                                            \
      _Pragma("unroll")                                                       \
      for (int r = 0; r < 4; ++r) z[mt][r] = 0.f;                             \
    _Pragma("unroll")                                                         \
    for (int mt = 0; mt < 2; ++mt)                                            \
      _Pragma("unroll")                                                       \
      for (int nt = 0; nt < 8; ++nt)                                          \
        _Pragma("unroll")                                                     \
        for (int r = 0; r < 4; ++r)                                           \
          z[mt][r] += exp2f(fmaf(acc[mt][nt][r], LOG2E, bov[nt]));            \
    _Pragma("unroll")                                                         \
    for (int mt = 0; mt < 2; ++mt)                                            \
      _Pragma("unroll")                                                       \
      for (int r = 0; r < 4; ++r) {                                           \
        _Pragma("unroll")                                                     \
        for (int off = 1; off < 16; off <<= 1)                                \
          z[mt][r] += __shfl_xor(z[mt][r], off);                              \
      }                                                                       \
    if (lr == 0) {                                                            \
      _Pragma("unroll")                                                       \
      for (int mt = 0; mt < 2; ++mt) {                                        \
        float4 v4;                                                            \
        v4.x = z[mt][0]; v4.y = z[mt][1]; v4.z = z[mt][2]; v4.w = z[mt][3];   \
        *(float4*)&pz[(size_t)(ch) * L + l0 + w * 32 + mt * 16 + lq * 4] = v4;\
      }                                                                       \
    }                                                                         \
  }

  // ---- chunk c0
  STAGE_HALF(c0, 0);
  __syncthreads();
  KG_BLOCK(0);
  __syncthreads();                       // protect Blds
  STAGE_HALF(c0, 1);
  __syncthreads();                       // drain
  KG_BLOCK(1);

  // preload epilogue biases + c1's first A-frags BEFORE issuing c1 DMA,
  // so their vmcnt wait does not drain the staging queue
  float bov[8];
  #pragma unroll
  for (int nt = 0; nt < 8; ++nt)
    bov[nt] = bo[c0 * 128 + nt * 16 + lr] * LOG2E;
  #pragma unroll
  for (int mt = 0; mt < 2; ++mt) af[0][mt] = aptr[mt][0];
  __syncthreads();                       // protect Blds (also drains above)
  STAGE_HALF(c1, 0);                     // DMA in flight during epilogue
  EPILOGUE(c0);                          // exp/shuffle tail hides DMA latency
  #pragma unroll
  for (int mt = 0; mt < 2; ++mt)
    #pragma unroll
    for (int nt = 0; nt < 8; ++nt) acc[mt][nt] = zero;
  __syncthreads();                       // drain c1 half 0

  // ---- chunk c1
  KG_BLOCK(0);
  __syncthreads();                       // protect Blds
  STAGE_HALF(c1, 1);
  __syncthreads();                       // drain
  KG_BLOCK(1);
  #pragma unroll
  for (int nt = 0; nt < 8; ++nt)
    bov[nt] = bo[c1 * 128 + nt * 16 + lr] * LOG2E;
  EPILOGUE(c1);

#undef STAGE_HALF
#undef KG_BLOCK
#undef EPILOGUE
}

// ---------------------------------------------------------------- kernel F
__global__ __launch_bounds__(256) void reduce_kernel(
    const float* __restrict__ pz, const float* __restrict__ tagl,
    float* __restrict__ out) {
  int l = blockIdx.x * 256 + threadIdx.x;
  float z = 0.f;
  for (int c = 0; c < NCH; ++c) z += pz[(size_t)c * L + l];
  float per = logf(z) - tagl[l];
  float v = per * (1.0f / (4096.0f + 1e-5f));
  #pragma unroll
  for (int off = 1; off < 64; off <<= 1) v += __shfl_xor(v, off);
  __shared__ float wsum[4];
  if ((threadIdx.x & 63) == 0) wsum[threadIdx.x >> 6] = v;
  __syncthreads();
  if (threadIdx.x == 0)
    atomicAdd(out, wsum[0] + wsum[1] + wsum[2] + wsum[3]);
}

// ---------------------------------------------------------------- launch
extern "C" void kernel_launch(void* const* d_in, const int* in_sizes, int n_in,
                              void* d_out, int out_size, void* d_ws,
                              size_t ws_size, hipStream_t stream) {
  const float* hidden = (const float*)d_in[0];
  const int* begins = (const int*)d_in[1];
  const int* ends = (const int*)d_in[2];
  const int* bids = (const int*)d_in[3];
  const int* tags = (const int*)d_in[4];
  const float* W1 = (const float*)d_in[5];
  const float* b1 = (const float*)d_in[6];
  const float* W2 = (const float*)d_in[7];
  const float* b2 = (const float*)d_in[8];
  const float* Wo = (const float*)d_in[9];
  const float* bo = (const float*)d_in[10];
  float* out = (float*)d_out;

  ushort* featb = (ushort*)d_ws;                       // L*256
  ushort* Wob = featb + (size_t)L * 256;               // V*256 (frag-major)
  ushort* spanb = Wob + (size_t)V * 256;               // L*1536
  ushort* W1b = spanb + (size_t)L * 1536;              // 256*1536
  ushort* W2b = W1b + (size_t)256 * 1536;              // 256*256
  // pz (NCH*L f32 = 4.1 MB) aliases spanb (12.6 MB): spanb dead after
  // feat_mfma_kernel; logits_kernel runs strictly after it in-stream.
  float* pz = (float*)spanb;
  float* tagl = (float*)(W2b + (size_t)256 * 256);     // L

  prep_kernel<<<4160, 256, 0, stream>>>(hidden, begins, ends, bids, spanb,
                                        W1, W1b, W2, W2b, Wo, Wob);
  feat_mfma_kernel<<<256, 256, 0, stream>>>(spanb, W1b, b1, W2b, b2, featb,
                                            out);
  logits_kernel<<<5024, 256, 0, stream>>>(featb, Wob, bo, tags, pz, tagl);
  reduce_kernel<<<L / 256, 256, 0, stream>>>(pz, tagl, out);
}

// Round 7
// 280.382 us; speedup vs baseline: 1.2600x; 1.0254x over previous
//
#include <hip/hip_runtime.h>
#include <math.h>

#define S 2048
#define B 16
#define H 512
#define L 4096
#define SMAX 16
#define LAB 256
#define V 32000
#define NCH 250          // V / 128 vocab chunks
#define LOG2E 1.44269504f

typedef __attribute__((ext_vector_type(8))) short short8;
typedef __attribute__((ext_vector_type(4))) float float4v;

__device__ inline ushort f2bf(float x) {
  union { float f; unsigned u; } c; c.f = x;
  unsigned r = c.u + 0x7fffu + ((c.u >> 16) & 1u);
  return (ushort)(r >> 16);
}
__device__ inline float bf2f(ushort h) {
  union { unsigned u; float f; } c; c.u = ((unsigned)h) << 16;
  return c.f;
}

// ---------------------------------------------------------------- kernel P
// Fused prep: blocks [0,2048) span gather; [2048,2144) W1 tcast;
// [2144,2160) W2 tcast; [2160,4160) Wo frag-major tcast.
__global__ __launch_bounds__(256) void prep_kernel(
    const float* __restrict__ hidden, const int* __restrict__ begins,
    const int* __restrict__ ends, const int* __restrict__ bids,
    ushort* __restrict__ spanb, const float* __restrict__ W1,
    ushort* __restrict__ W1b, const float* __restrict__ W2,
    ushort* __restrict__ W2b, const float* __restrict__ Wo,
    ushort* __restrict__ Wob) {
  __shared__ ushort tile[64 * 72];
  int bid = blockIdx.x;
  int t = threadIdx.x;

  if (bid < 2048) {                      // ---- span gather
    int sub = t >> 7, tt = t & 127;
    int l = bid * 2 + sub;
    int b = bids[l], s0 = begins[l], s1 = ends[l];
    const float4* hidv = (const float4*)hidden;
    float4 lf = hidv[((size_t)(s0 - 1) * B + b) * 128 + tt];
    float4 rf = hidv[((size_t)s1 * B + b) * 128 + tt];
    float4 m = make_float4(0.f, 0.f, 0.f, 0.f);
    int len = s1 - s0;
    for (int j = 0; j < len; ++j) {
      float4 g = hidv[((size_t)(s0 + j) * B + b) * 128 + tt];
      m.x += g.x; m.y += g.y; m.z += g.z; m.w += g.w;
    }
    float inv = 1.0f / (float)len;
    ushort* sp = spanb + (size_t)l * 1536;
    ushort4 u;
    u.x = f2bf(lf.x); u.y = f2bf(lf.y); u.z = f2bf(lf.z); u.w = f2bf(lf.w);
    *(ushort4*)&sp[tt * 4] = u;
    u.x = f2bf(m.x * inv); u.y = f2bf(m.y * inv);
    u.z = f2bf(m.z * inv); u.w = f2bf(m.w * inv);
    *(ushort4*)&sp[512 + tt * 4] = u;
    u.x = f2bf(rf.x); u.y = f2bf(rf.y); u.z = f2bf(rf.z); u.w = f2bf(rf.w);
    *(ushort4*)&sp[1024 + tt * 4] = u;
    return;
  }

  // ---- transpose+cast tiles
  const float* src; ushort* dst; int K, N, n0, k0; bool wo = false;
  if (bid < 2144) {
    int u = bid - 2048; src = W1; dst = W1b; K = 1536; N = 256;
    n0 = (u & 3) * 64; k0 = (u >> 2) * 64;
  } else if (bid < 2160) {
    int u = bid - 2144; src = W2; dst = W2b; K = 256; N = 256;
    n0 = (u & 3) * 64; k0 = (u >> 2) * 64;
  } else {
    int u = bid - 2160; src = Wo; dst = Wob; K = 256; N = V;
    n0 = (u % 500) * 64; k0 = (u / 500) * 64; wo = true;
  }
  #pragma unroll
  for (int p = 0; p < 16; ++p) {
    int k = p * 4 + (t >> 6);
    int n = t & 63;
    tile[n * 72 + k] = f2bf(src[(size_t)(k0 + k) * N + n0 + n]);
  }
  __syncthreads();
  if (!wo) {
    #pragma unroll
    for (int p = 0; p < 2; ++p) {
      int idx = p * 256 + t;
      int n = idx >> 3, c = idx & 7;
      *(uint4*)&dst[(size_t)(n0 + n) * K + k0 + c * 8] =
          *(const uint4*)&tile[n * 72 + c * 8];
    }
  } else {
    // fragment-major: f = (((c*2+kh)*4+k4)*8+nt)*64 + lq*16 + lr
    #pragma unroll
    for (int p = 0; p < 2; ++p) {
      int idx = p * 256 + t;
      int n = idx >> 3, c8 = idx & 7;
      int v = n0 + n, k = k0 + c8 * 8;
      int c = v >> 7, nt = (v >> 4) & 7, lr = v & 15;
      int kh = k >> 7, k4 = (k >> 5) & 3, lq = (k >> 3) & 3;
      size_t f = ((((size_t)c * 2 + kh) * 4 + k4) * 8 + nt) * 64 + lq * 16 + lr;
      *(uint4*)&dst[f * 8] = *(const uint4*)&tile[n * 72 + c8 * 8];
    }
  }
}

// ---------------------------------------------------------------- kernel C
// MFMA MLP: featb = bf16( sigmoid(spanb@W1+b1) @ W2 + b2 )
// 256 blocks x 16 labels, A/B direct from global (L2-hot), LDS only for
// the H transpose. Also zeroes `out` (replaces the memset launch).
__global__ __launch_bounds__(256) void feat_mfma_kernel(
    const ushort* __restrict__ spanb, const ushort* __restrict__ W1b,
    const float* __restrict__ b1, const ushort* __restrict__ W2b,
    const float* __restrict__ b2, ushort* __restrict__ featb,
    float* __restrict__ out) {
  __shared__ ushort Hs[16 * 264];
  int tid = threadIdx.x;
  if (blockIdx.x == 0 && tid == 0) *out = 0.f;   // zero accumulator output
  int w = tid >> 6, lane = tid & 63;
  int lr = lane & 15, lq = lane >> 4;
  int l0 = blockIdx.x * 16;

  const short8* arow = (const short8*)(spanb + (size_t)(l0 + lr) * 1536 + lq * 8);
  const short8* brow[4];
  #pragma unroll
  for (int nt = 0; nt < 4; ++nt)
    brow[nt] = (const short8*)(W1b + (size_t)(w * 64 + nt * 16 + lr) * 1536 + lq * 8);

  float4v acc[4];
  float4v zero = {0.f, 0.f, 0.f, 0.f};
  #pragma unroll
  for (int nt = 0; nt < 4; ++nt) acc[nt] = zero;

  short8 af[2], bf[2][4];
  af[0] = arow[0];
  #pragma unroll
  for (int nt = 0; nt < 4; ++nt) bf[0][nt] = brow[nt][0];

  #pragma unroll
  for (int s = 0; s < 48; ++s) {
    int cur = s & 1, nxt = cur ^ 1;
    if (s < 47) {
      af[nxt] = arow[(s + 1) * 4];
      #pragma unroll
      for (int nt = 0; nt < 4; ++nt) bf[nxt][nt] = brow[nt][(s + 1) * 4];
    }
    #pragma unroll
    for (int nt = 0; nt < 4; ++nt)
      acc[nt] = __builtin_amdgcn_mfma_f32_16x16x32_bf16(
          af[cur], bf[cur][nt], acc[nt], 0, 0, 0);
  }

  {
    #pragma unroll
    for (int nt = 0; nt < 4; ++nt) {
      float b1v = b1[w * 64 + nt * 16 + lr];
      #pragma unroll
      for (int r = 0; r < 4; ++r) {
        int row = lq * 4 + r;
        float h = 1.0f / (1.0f + __expf(-(acc[nt][r] + b1v)));
        Hs[row * 264 + w * 64 + nt * 16 + lr] = f2bf(h);
      }
    }
  }
  __syncthreads();

  const short8* wrow[4];
  #pragma unroll
  for (int nt = 0; nt < 4; ++nt)
    wrow[nt] = (const short8*)(W2b + (size_t)(w * 64 + nt * 16 + lr) * 256 + lq * 8);

  float4v acc2[4];
  #pragma unroll
  for (int nt = 0; nt < 4; ++nt) acc2[nt] = zero;

  short8 bf2[2][4];
  #pragma unroll
  for (int nt = 0; nt < 4; ++nt) bf2[0][nt] = wrow[nt][0];

  #pragma unroll
  for (int s = 0; s < 8; ++s) {
    int cur = s & 1, nxt = cur ^ 1;
    if (s < 7) {
      #pragma unroll
      for (int nt = 0; nt < 4; ++nt) bf2[nxt][nt] = wrow[nt][(s + 1) * 4];
    }
    short8 af2 = *(const short8*)&Hs[lr * 264 + s * 32 + lq * 8];
    #pragma unroll
    for (int nt = 0; nt < 4; ++nt)
      acc2[nt] = __builtin_amdgcn_mfma_f32_16x16x32_bf16(
          af2, bf2[cur][nt], acc2[nt], 0, 0, 0);
  }

  {
    #pragma unroll
    for (int nt = 0; nt < 4; ++nt) {
      float b2v = b2[w * 64 + nt * 16 + lr];
      #pragma unroll
      for (int r = 0; r < 4; ++r) {
        int row = lq * 4 + r;
        int col = w * 64 + nt * 16 + lr;
        featb[(size_t)(l0 + row) * 256 + col] = f2bf(acc2[nt][r] + b2v);
      }
    }
  }
}

// ---------------------------------------------------------------- kernel D
// logits + sumexp partials. R5 per-wave code, restructured:
//  - 512-thread blocks (8 waves), 256 labels x 128 vocab: staged B feeds
//    2x the MFMA work -> stage L2 traffic and barrier count per MFMA halve
//  - double-buffered 32KB halves: h1 DMA ISSUED before computing h0
//    (compute h0 is LDS-only, so the DMA rides under ~4us of MFMA and the
//    vmcnt(0) at the h0->h1 barrier finds it complete). 2 barriers/chunk.
//  - unified regfile budget: 64 arch + 64 AGPR = 128 -> launch_bounds(512,4)
//    = 16 waves/CU (2 blocks), same occupancy as R5 with half the blocks.
__global__ __launch_bounds__(512, 4) void logits2_kernel(
    const ushort* __restrict__ featb, const ushort* __restrict__ Wob,
    const float* __restrict__ bo, float* __restrict__ pz) {
  __shared__ ushort Blds[2][16384];      // 2 x 32 KB halves, fragment-major
  int tid = threadIdx.x;
  int w = tid >> 6, lane = tid & 63;
  int lr = lane & 15, lq = lane >> 4;
  int l0 = blockIdx.x * 256;
  int v0 = blockIdx.y * 128;

  // per-mt global A pointers; k-step advance = 32 ushorts = 4 short8
  const short8* aptr[2];
  #pragma unroll
  for (int mt = 0; mt < 2; ++mt)
    aptr[mt] = (const short8*)(featb +
        (size_t)(l0 + w * 32 + mt * 16 + lr) * 256 + lq * 8);

  float4v acc[2][8];
  float4v zero = {0.f, 0.f, 0.f, 0.f};
  #pragma unroll
  for (int mt = 0; mt < 2; ++mt)
    #pragma unroll
    for (int nt = 0; nt < 8; ++nt) acc[mt][nt] = zero;

  short8 af[2][2];
  #pragma unroll
  for (int mt = 0; mt < 2; ++mt) af[0][mt] = aptr[mt][0];

#define STAGE_HALF(buf, kh)                                                   \
  {                                                                           \
    const uint4* src4 = (const uint4*)(Wob +                                  \
        (size_t)blockIdx.y * 32768 + (size_t)(kh) * 16384);                   \
    _Pragma("unroll")                                                         \
    for (int p = 0; p < 4; ++p) {                                             \
      int idx = p * 512 + tid;                                                \
      __builtin_amdgcn_global_load_lds(                                       \
          (const __attribute__((address_space(1))) unsigned int*)(src4 + idx),\
          (__attribute__((address_space(3))) unsigned int*)                   \
              &Blds[buf][(size_t)idx * 8],                                    \
          16, 0, 0);                                                          \
    }                                                                         \
  }

#define KG_BLOCK(buf, kh)                                                     \
  _Pragma("unroll")                                                           \
  for (int k4 = 0; k4 < 4; ++k4) {                                            \
    int kg = (kh) * 4 + k4;                                                   \
    int cur = kg & 1, nxt = cur ^ 1;                                          \
    if (kg < 7) {                                                             \
      _Pragma("unroll")                                                       \
      for (int mt = 0; mt < 2; ++mt)                                          \
        af[nxt][mt] = aptr[mt][(kg + 1) * 4];                                 \
    }                                                                         \
    short8 bf[8];                                                             \
    _Pragma("unroll")                                                         \
    for (int nt = 0; nt < 8; ++nt)                                            \
      bf[nt] = *(const short8*)                                               \
          &Blds[buf][(size_t)(((k4 * 8 + nt) * 64) + lane) * 8];              \
    __builtin_amdgcn_s_setprio(1);                                            \
    _Pragma("unroll")                                                         \
    for (int mt = 0; mt < 2; ++mt)                                            \
      _Pragma("unroll")                                                       \
      for (int nt = 0; nt < 8; ++nt)                                          \
        acc[mt][nt] = __builtin_amdgcn_mfma_f32_16x16x32_bf16(                \
            af[cur][mt], bf[nt], acc[mt][nt], 0, 0, 0);                       \
    __builtin_amdgcn_s_setprio(0);                                            \
  }

  STAGE_HALF(0, 0);                      // stage h0
  __syncthreads();                       // h0 ready
  STAGE_HALF(1, 1);                      // h1 DMA in flight under compute h0
  KG_BLOCK(0, 0);                        // compute h0 (LDS-only)
  __syncthreads();                       // h1 ready (DMA long done)
  KG_BLOCK(1, 1);                        // compute h1

#undef STAGE_HALF
#undef KG_BLOCK

  // epilogue: z[row] = sum_cols exp(logit + bo), no max (logits bounded)
  // bov loaded HERE to keep in-loop arch regs <= 64
  float bov[8];
  #pragma unroll
  for (int nt = 0; nt < 8; ++nt)
    bov[nt] = bo[v0 + nt * 16 + lr] * LOG2E;
  float z[2][4];
  #pragma unroll
  for (int mt = 0; mt < 2; ++mt)
    #pragma unroll
    for (int r = 0; r < 4; ++r) z[mt][r] = 0.f;
  #pragma unroll
  for (int mt = 0; mt < 2; ++mt)
    #pragma unroll
    for (int nt = 0; nt < 8; ++nt)
      #pragma unroll
      for (int r = 0; r < 4; ++r)
        z[mt][r] += exp2f(fmaf(acc[mt][nt][r], LOG2E, bov[nt]));
  #pragma unroll
  for (int mt = 0; mt < 2; ++mt)
    #pragma unroll
    for (int r = 0; r < 4; ++r) {
      #pragma unroll
      for (int off = 1; off < 16; off <<= 1)
        z[mt][r] += __shfl_xor(z[mt][r], off);
    }
  if (lr == 0) {
    int ch = blockIdx.y;
    #pragma unroll
    for (int mt = 0; mt < 2; ++mt) {
      float4 v4;
      v4.x = z[mt][0]; v4.y = z[mt][1]; v4.z = z[mt][2]; v4.w = z[mt][3];
      *(float4*)&pz[(size_t)ch * L + l0 + w * 32 + mt * 16 + lq * 4] = v4;
    }
  }
}

// ---------------------------------------------------------------- kernel E
// Exact tag logit from fragment-major Wob (same bf16 values as pz path).
// Separate kernel again: fusing it into logits polluted that dispatch
// (FETCH +43MB, WRITE +89MB, +17.5us) -- R6 post-mortem.
__global__ __launch_bounds__(256) void tag_kernel(
    const ushort* __restrict__ featb, const ushort* __restrict__ Wob,
    const float* __restrict__ bo, const int* __restrict__ tags,
    float* __restrict__ tagl) {
  int l = blockIdx.x * 4 + (threadIdx.x >> 6);
  int lane = threadIdx.x & 63;
  int tg = tags[l];
  int c = tg >> 7, nt = (tg >> 4) & 7, lr = tg & 15;
  int k0 = lane << 2;
  int kh = k0 >> 7, k4 = (k0 >> 5) & 3, lq = (k0 >> 3) & 3, e = k0 & 7;
  size_t f = ((((size_t)c * 2 + kh) * 4 + k4) * 8 + nt) * 64 + lq * 16 + lr;
  ushort4 wa = *(const ushort4*)&Wob[f * 8 + e];
  ushort4 fa = *(const ushort4*)&featb[(size_t)l * 256 + k0];
  float s = bf2f(fa.x) * bf2f(wa.x) + bf2f(fa.y) * bf2f(wa.y) +
            bf2f(fa.z) * bf2f(wa.z) + bf2f(fa.w) * bf2f(wa.w);
  #pragma unroll
  for (int off = 1; off < 64; off <<= 1) s += __shfl_xor(s, off);
  if (lane == 0) tagl[l] = s + bo[tg];
}

// ---------------------------------------------------------------- kernel F
__global__ __launch_bounds__(256) void reduce_kernel(
    const float* __restrict__ pz, const float* __restrict__ tagl,
    float* __restrict__ out) {
  int l = blockIdx.x * 256 + threadIdx.x;
  float z = 0.f;
  #pragma unroll 5
  for (int c = 0; c < NCH; ++c) z += pz[(size_t)c * L + l];
  float per = logf(z) - tagl[l];
  float v = per * (1.0f / (4096.0f + 1e-5f));
  #pragma unroll
  for (int off = 1; off < 64; off <<= 1) v += __shfl_xor(v, off);
  __shared__ float wsum[4];
  if ((threadIdx.x & 63) == 0) wsum[threadIdx.x >> 6] = v;
  __syncthreads();
  if (threadIdx.x == 0)
    atomicAdd(out, wsum[0] + wsum[1] + wsum[2] + wsum[3]);
}

// ---------------------------------------------------------------- launch
extern "C" void kernel_launch(void* const* d_in, const int* in_sizes, int n_in,
                              void* d_out, int out_size, void* d_ws,
                              size_t ws_size, hipStream_t stream) {
  const float* hidden = (const float*)d_in[0];
  const int* begins = (const int*)d_in[1];
  const int* ends = (const int*)d_in[2];
  const int* bids = (const int*)d_in[3];
  const int* tags = (const int*)d_in[4];
  const float* W1 = (const float*)d_in[5];
  const float* b1 = (const float*)d_in[6];
  const float* W2 = (const float*)d_in[7];
  const float* b2 = (const float*)d_in[8];
  const float* Wo = (const float*)d_in[9];
  const float* bo = (const float*)d_in[10];
  float* out = (float*)d_out;

  ushort* featb = (ushort*)d_ws;                       // L*256
  ushort* Wob = featb + (size_t)L * 256;               // V*256 (frag-major)
  ushort* spanb = Wob + (size_t)V * 256;               // L*1536
  ushort* W1b = spanb + (size_t)L * 1536;              // 256*1536
  ushort* W2b = W1b + (size_t)256 * 1536;              // 256*256
  // pz (NCH*L f32 = 4.1 MB) aliases spanb (12.6 MB): spanb dead after
  // feat_mfma_kernel; logits2 runs strictly after it in-stream.
  float* pz = (float*)spanb;
  float* tagl = (float*)(W2b + (size_t)256 * 256);     // L

  prep_kernel<<<4160, 256, 0, stream>>>(hidden, begins, ends, bids, spanb,
                                        W1, W1b, W2, W2b, Wo, Wob);
  feat_mfma_kernel<<<256, 256, 0, stream>>>(spanb, W1b, b1, W2b, b2, featb,
                                            out);
  logits2_kernel<<<dim3(16, NCH), 512, 0, stream>>>(featb, Wob, bo, pz);
  tag_kernel<<<L / 4, 256, 0, stream>>>(featb, Wob, bo, tags, tagl);
  reduce_kernel<<<L / 256, 256, 0, stream>>>(pz, tagl, out);
}